// Round 1
// baseline (1001.836 us; speedup 1.0000x reference)
//
#include <hip/hip_runtime.h>

#define NK 19
#define NC 64
#define HW (512*512)
#define BLOCK 256
#define NBLOCKS 2048        // 8192 waves = 128 (batch,cgroup) combos x 64 pixel-subranges
#define SUMS (NK*NC)        // 1216
#define MAXCOPIES 64
#define CHUNKS 16           // chunks per wave
#define CPX 256             // pixels per chunk (64 lanes x 4)

// ---------------------------------------------------------------------------
// Kernel 1: per-class feature sums, barrier-free streaming (no LDS at all).
// Wave owns a fixed 4-channel group {c0..c0+3}; lane owns 4 consecutive pixels.
// One label compare per (pixel,class) serves 4 FMAs -> same VALU efficiency as
// the old LDS-transpose version, but with zero barriers and zero LDS, so HBM
// latency is hidden by occupancy (16 waves/CU) instead of fought by barriers.
// Loads: 4x float4 (1 KiB/wave-instr, fully coalesced) + 1x int4 labels.
// Labels are re-read once per channel-group (16x) -> served by L2 (1 MiB/batch).
// ---------------------------------------------------------------------------
__global__ __launch_bounds__(BLOCK, 4) void accum_kernel(
    const float* __restrict__ x, const int* __restrict__ t,
    float* __restrict__ ws, int copymask) {
  const int tid = threadIdx.x;
  const int wv = tid >> 6, ln = tid & 63;
  const int wid   = (blockIdx.x << 2) + wv;   // 0..8191
  const int combo = wid >> 6;                 // 0..127 = (batch, cgroup)
  const int batch = combo >> 4;               // 0..7
  const int c0    = (combo & 15) << 2;        // channel base 0,4,...,60
  const int sub   = wid & 63;                 // pixel sub-range within batch
  const size_t pix0 = (size_t)sub * (CHUNKS * CPX);   // 4096 px per wave

  const float* xr0 = x + (size_t)(batch * NC + c0) * HW + pix0 + (ln << 2);
  const float* xr1 = xr0 + HW;
  const float* xr2 = xr1 + HW;
  const float* xr3 = xr2 + HW;
  const int*   tr  = t + (size_t)batch * HW + pix0 + (ln << 2);

  float acc[NK][4];
#pragma unroll
  for (int k = 0; k < NK; ++k)
#pragma unroll
    for (int j = 0; j < 4; ++j) acc[k][j] = 0.0f;

#pragma unroll 1
  for (int ch = 0; ch < CHUNKS; ++ch) {
    const int off = ch * CPX;
    // issue all 5 loads together; no barriers anywhere -> stays in flight
    const float4 v0 = *reinterpret_cast<const float4*>(xr0 + off);
    const float4 v1 = *reinterpret_cast<const float4*>(xr1 + off);
    const float4 v2 = *reinterpret_cast<const float4*>(xr2 + off);
    const float4 v3 = *reinterpret_cast<const float4*>(xr3 + off);
    const int4   lb = *reinterpret_cast<const int4*>(tr + off);
    const float a0[4] = {v0.x, v0.y, v0.z, v0.w};
    const float a1[4] = {v1.x, v1.y, v1.z, v1.w};
    const float a2[4] = {v2.x, v2.y, v2.z, v2.w};
    const float a3[4] = {v3.x, v3.y, v3.z, v3.w};
    const int  lbs[4] = {lb.x, lb.y, lb.z, lb.w};
#pragma unroll
    for (int q = 0; q < 4; ++q) {
      const int lab = lbs[q];
      const float f0 = a0[q], f1 = a1[q], f2 = a2[q], f3 = a3[q];
#pragma unroll
      for (int k = 0; k < NK; ++k) {
        const float sel = (lab == k) ? 1.0f : 0.0f;   // 1 cmp + 1 cndmask serves 4 FMAs
        acc[k][0] = fmaf(f0, sel, acc[k][0]);
        acc[k][1] = fmaf(f1, sel, acc[k][1]);
        acc[k][2] = fmaf(f2, sel, acc[k][2]);
        acc[k][3] = fmaf(f3, sel, acc[k][3]);
      }
    }
  }

  // full 64-lane butterfly: every lane ends with the wave totals (all static idx)
#pragma unroll
  for (int k = 0; k < NK; ++k)
#pragma unroll
    for (int j = 0; j < 4; ++j) {
      float v = acc[k][j];
      v += __shfl_xor(v, 1, 64);  v += __shfl_xor(v, 2, 64);
      v += __shfl_xor(v, 4, 64);  v += __shfl_xor(v, 8, 64);
      v += __shfl_xor(v, 16, 64); v += __shfl_xor(v, 32, 64);
      acc[k][j] = v;
    }

  // one flush per wave: 76 fp32 atomics into a rotating copy (~8 hits/addr)
  if (ln == 0) {
    float* base = ws + (size_t)(wid & copymask) * SUMS + c0;
#pragma unroll
    for (int k = 0; k < NK; ++k) {
      unsafeAtomicAdd(base + k * NC + 0, acc[k][0]);
      unsafeAtomicAdd(base + k * NC + 1, acc[k][1]);
      unsafeAtomicAdd(base + k * NC + 2, acc[k][2]);
      unsafeAtomicAdd(base + k * NC + 3, acc[k][3]);
    }
  }
}

// ---------------------------------------------------------------------------
// Kernel 2: label histogram in registers (no per-element atomics) - unchanged
// ---------------------------------------------------------------------------
__global__ __launch_bounds__(BLOCK) void hist_kernel(
    const int* __restrict__ t, float* __restrict__ cnts) {
  int cnt[NK];
#pragma unroll
  for (int k = 0; k < NK; ++k) cnt[k] = 0;
  const int tid = threadIdx.x;
  const size_t base = (size_t)blockIdx.x * 8192;
#pragma unroll
  for (int q = 0; q < 8; ++q) {
    const int4 l4 = *reinterpret_cast<const int4*>(t + base + q * 1024 + tid * 4);
#pragma unroll
    for (int k = 0; k < NK; ++k)
      cnt[k] += (l4.x == k) + (l4.y == k) + (l4.z == k) + (l4.w == k);
  }
#pragma unroll
  for (int k = 0; k < NK; ++k) {
    int v = cnt[k];
    v += __shfl_xor(v, 1, 64);  v += __shfl_xor(v, 2, 64);
    v += __shfl_xor(v, 4, 64);  v += __shfl_xor(v, 8, 64);
    v += __shfl_xor(v, 16, 64); v += __shfl_xor(v, 32, 64);
    cnt[k] = v;
  }
  if ((tid & 63) == 0) {
#pragma unroll
    for (int k = 0; k < NK; ++k)
      unsafeAtomicAdd(cnts + k, (float)cnt[k]);
  }
}

// ---------------------------------------------------------------------------
// Kernel 3: reduce copies -> centers -> norms -> 19x19 cosine -> scalar
// ---------------------------------------------------------------------------
__global__ __launch_bounds__(512) void finalize_kernel(
    const float* __restrict__ ws, const float* __restrict__ cnts,
    float* __restrict__ out, int ncopies) {
  __shared__ float cen[SUMS];   // [k*64 + c]
  __shared__ float invn[NK];
  __shared__ float cc[NK];
  __shared__ float red[8];

  const int tid = threadIdx.x;
  if (tid < NK) cc[tid] = fmaxf(cnts[tid], 1.0f);
  __syncthreads();

  for (int i = tid; i < SUMS; i += 512) {
    float s = 0.0f;
    for (int r = 0; r < ncopies; ++r) s += ws[(size_t)r * SUMS + i];
    cen[i] = s / cc[i >> 6];
  }
  __syncthreads();

  if (tid < NK) {
    float sq = 0.0f;
    for (int c = 0; c < NC; ++c) { float v = cen[tid * NC + c]; sq += v * v; }
    invn[tid] = 1.0f / fmaxf(sqrtf(sq), 1e-8f);
  }
  __syncthreads();

  float contrib = 0.0f;
  if (tid < NK * NK) {
    int i = tid / NK, j = tid - (tid / NK) * NK;
    float dot = 0.0f;
    for (int c = 0; c < NC; ++c) dot += cen[i * NC + c] * cen[j * NC + c];
    float S = dot * invn[i] * invn[j];
    contrib = (i == j) ? (1.0f - S) : fmaxf(S, 0.0f);
  }
  for (int off = 32; off > 0; off >>= 1) contrib += __shfl_down(contrib, off, 64);
  if ((tid & 63) == 0) red[tid >> 6] = contrib;
  __syncthreads();
  if (tid == 0) {
    float s = 0.0f;
    for (int w = 0; w < 8; ++w) s += red[w];
    out[0] = s / 6859.0f;  // / K^3
  }
}

extern "C" void kernel_launch(void* const* d_in, const int* in_sizes, int n_in,
                              void* d_out, int out_size, void* d_ws, size_t ws_size,
                              hipStream_t stream) {
  const float* x = (const float*)d_in[0];
  const int*   t = (const int*)d_in[1];
  float* ws = (float*)d_ws;

  // as many power-of-2 rotating copies as the workspace allows (<=64)
  int ncopies = 1;
  while (ncopies < MAXCOPIES &&
         (size_t)(ncopies * 2 * SUMS + 32) * sizeof(float) <= ws_size)
    ncopies *= 2;
  float* cnts = ws + (size_t)ncopies * SUMS;

  hipMemsetAsync(d_ws, 0, ((size_t)ncopies * SUMS + 32) * sizeof(float), stream);
  accum_kernel<<<NBLOCKS, BLOCK, 0, stream>>>(x, t, ws, ncopies - 1);
  hist_kernel<<<256, BLOCK, 0, stream>>>(t, cnts);
  finalize_kernel<<<1, 512, 0, stream>>>(ws, cnts, (float*)d_out, ncopies);
}